// Round 8
// baseline (92.143 us; speedup 1.0000x reference)
//
#include <hip/hip_runtime.h>
#include <hip/hip_fp16.h>

#define RH 128
#define RW 128
#define CS 21    // src channels
#define IH 512
#define IW 512
#define NPIX (RH * RW)
#define P 13         // dy split factor
#define SPITCH 160   // padded src row pitch (halves): 12 zero | 128 | 20 zero
#define SCH (RH * SPITCH)   // per-channel plane stride = 20480
#define IPITCH 152   // padded im row pitch (half4 units): 12 reflect | 128 | 12 reflect

// ---------------- K1a-H: horizontal antialiased downsample 512x512x21 -> tmpH[512][160][21] fp16 ----------------
__global__ void ds_src_h_kernel(const float* __restrict__ in, __half* __restrict__ tmpH) {
    int idx = blockIdx.x * blockDim.x + threadIdx.x;
    if (idx >= IH * SPITCH * CS) return;
    int c = idx % CS;
    int t = idx / CS;
    int xp = t % SPITCH;
    int y = t / SPITCH;                 // input row 0..511
    int x = xp - 12;
    if (x < 0 || x >= RW) { tmpH[idx] = __float2half(0.f); return; }

    float sx = 4.f * x + 1.5f;
    float wx[8]; int jx[8]; float wxs = 0.f;
#pragma unroll
    for (int k = 0; k < 8; ++k) {
        int j = 4 * x - 2 + k;
        float w = 1.f - fabsf(sx - (float)j) * 0.25f;
        if (j < 0 || j >= IW) { w = 0.f; j = 0; }
        jx[k] = j; wx[k] = w; wxs += w;
    }
    const float* row = in + (size_t)y * IW * CS + c;
    float s = 0.f;
#pragma unroll
    for (int b = 0; b < 8; ++b) s += wx[b] * row[jx[b] * CS];
    tmpH[idx] = __float2half(s / wxs);
}

// ---------------- K1a-V: vertical pass tmpH -> planar zero-padded srcP[21][128][160] fp16 ----------------
__global__ void ds_src_v_kernel(const __half* __restrict__ tmpH, __half* __restrict__ srcP) {
    int idx = blockIdx.x * blockDim.x + threadIdx.x;
    if (idx >= RH * SPITCH * CS) return;
    int c = idx % CS;
    int t = idx / CS;
    int xp = t % SPITCH;
    int y = t / SPITCH;                 // output row 0..127

    float sy = 4.f * y + 1.5f;
    float wy[8]; int jy[8]; float wys = 0.f;
#pragma unroll
    for (int k = 0; k < 8; ++k) {
        int j = 4 * y - 2 + k;
        float w = 1.f - fabsf(sy - (float)j) * 0.25f;
        if (j < 0 || j >= IH) { w = 0.f; j = 0; }
        jy[k] = j; wy[k] = w; wys += w;
    }
    float s = 0.f;
#pragma unroll
    for (int a = 0; a < 8; ++a)
        s += wy[a] * __half2float(tmpH[((size_t)jy[a] * SPITCH + xp) * CS + c]);
    srcP[(size_t)c * SCH + y * SPITCH + xp] = __float2half(s / wys);
}

// ---------------- K1b: downsample im 512->128, fp16 x4, horizontally reflect-padded ----------------
__global__ void downsample_im_kernel(const float* __restrict__ in, __half* __restrict__ imh) {
    int idx = blockIdx.x * blockDim.x + threadIdx.x;
    if (idx >= RH * IPITCH) return;
    int xp = idx % IPITCH;
    int y = idx / IPITCH;
    int gx = xp - 12;
    gx = gx < 0 ? -gx : (gx > RW - 1 ? 2 * (RW - 1) - gx : gx);

    float wy[8], wx[8];
    int jy[8], jx[8];
    float sy = 4.f * y + 1.5f, sx = 4.f * gx + 1.5f;
    float wys = 0.f, wxs = 0.f;
#pragma unroll
    for (int k = 0; k < 8; ++k) {
        int j = 4 * y - 2 + k;
        float w = 1.f - fabsf(sy - (float)j) * 0.25f;
        if (j < 0 || j >= IH) { w = 0.f; j = 0; }
        jy[k] = j; wy[k] = w; wys += w;
        int j2 = 4 * gx - 2 + k;
        float w2 = 1.f - fabsf(sx - (float)j2) * 0.25f;
        if (j2 < 0 || j2 >= IW) { w2 = 0.f; j2 = 0; }
        jx[k] = j2; wx[k] = w2; wxs += w2;
    }
    float inv = 1.f / (wys * wxs);
    float s0 = 0.f, s1 = 0.f, s2 = 0.f;
#pragma unroll
    for (int a = 0; a < 8; ++a) {
        const float* row = in + (size_t)(jy[a] * IW) * 3;
        float r0 = 0.f, r1 = 0.f, r2 = 0.f;
#pragma unroll
        for (int b = 0; b < 8; ++b) {
            const float* pp = row + jx[b] * 3;
            r0 += wx[b] * pp[0];
            r1 += wx[b] * pp[1];
            r2 += wx[b] * pp[2];
        }
        s0 += wy[a] * r0; s1 += wy[a] * r1; s2 += wy[a] * r2;
    }
    __half* o = imh + (size_t)idx * 4;
    o[0] = __float2half(s0 * inv);
    o[1] = __float2half(s1 * inv);
    o[2] = __float2half(s2 * inv);
    o[3] = __float2half(0.f);
}

// ---------------- K2: joint bilateral, fp16 planar src + fp16 im, P=13 dy split ----------------
__global__ __launch_bounds__(256, 4) void bilateral_kernel(
        const __half* __restrict__ srcP,  // [21][128][160] fp16 zero-padded
        const float2* __restrict__ imf2,  // [128][152] as 4xfp16 per element, reflect-padded
        float* __restrict__ part) {       // [13][21][NPIX] f32
    int wid = (blockIdx.x << 2) + (threadIdx.x >> 6);   // 0..3327
    int lane = threadIdx.x & 63;
    int p = wid >> 8;                                   // 0..12
    int pxw = wid & 255;
    int h = pxw & 1;
    int y = pxw >> 1;
    int x = (h << 6) + lane;

    float2 craw = imf2[y * IPITCH + x + 12];
    __half2 ch01 = *reinterpret_cast<const __half2*>(&craw.x);
    __half2 ch23 = *reinterpret_cast<const __half2*>(&craw.y);
    float2 crg = __half22float2(ch01);
    float c0 = crg.x, c1 = crg.y, c2 = __half2float(__low2half(ch23));

    float acc[CS];
#pragma unroll
    for (int c = 0; c < CS; ++c) acc[c] = 0.f;

    for (int dy = p; dy < 25; dy += P) {
        int ry = y + dy - 12;
        if (ry < 0 || ry >= RH) continue;               // wave-uniform; src zero-pad
        float fdy = (float)(dy - 12);
        float gy = fdy * fdy;
        const __half* srow = srcP + ry * SPITCH + x;    // + c*SCH + dx
        const float2* irow = imf2 + ry * IPITCH + x;    // + dx
#pragma unroll 5
        for (int dx = 0; dx < 25; ++dx) {
            float2 raw = irow[dx];
            __half2 h01 = *reinterpret_cast<const __half2*>(&raw.x);
            __half2 h23 = *reinterpret_cast<const __half2*>(&raw.y);
            float2 rg = __half22float2(h01);
            float d0 = rg.x - c0;
            float d1 = rg.y - c1;
            float d2 = __half2float(__low2half(h23)) - c2;
            float fdx = (float)(dx - 12);
            float e = -(d0 * d0 + d1 * d1 + d2 * d2) * (1.f / 18.f)
                      - (gy + fdx * fdx) * (1.f / 128.f);
            float cw = __expf(e);
#pragma unroll
            for (int c = 0; c < CS; ++c)
                acc[c] = fmaf(cw, __half2float(srow[c * SCH + dx]), acc[c]);
        }
    }
    int pix = (y << 7) + x;
#pragma unroll
    for (int c = 0; c < CS; ++c)
        part[((size_t)(p * CS + c) << 14) + pix] = acc[c];
}

// ---------------- K2b: reduce partials -> out_r fp16 ----------------
__global__ void reduce_kernel(const float* __restrict__ part, __half* __restrict__ outr) {
    int t = blockIdx.x * blockDim.x + threadIdx.x;
    if (t >= CS * NPIX) return;
    int c = t >> 14;
    int pix = t & (NPIX - 1);
    float s = 0.f;
#pragma unroll
    for (int p = 0; p < P; ++p)
        s += part[((size_t)(p * CS + c) << 14) + pix];
    outr[(size_t)pix * CS + c] = __float2half(s);
}

// ---------------- K3: bilinear upsample 128 -> 512 ----------------
__global__ void upsample_kernel(const __half* __restrict__ inr, float* __restrict__ out, int total) {
    int idx = blockIdx.x * blockDim.x + threadIdx.x;
    if (idx >= total) return;
    int c = idx % CS;
    int t = idx / CS;
    int X = t % IW, Y = t / IW;
    float fy = 0.25f * (float)Y - 0.375f;
    float fx = 0.25f * (float)X - 0.375f;
    int y0 = (int)floorf(fy); float ty = fy - (float)y0;
    int x0 = (int)floorf(fx); float tx = fx - (float)x0;
    int y1 = y0 + 1, x1 = x0 + 1;
    y0 = min(max(y0, 0), RH - 1); y1 = min(max(y1, 0), RH - 1);
    x0 = min(max(x0, 0), RW - 1); x1 = min(max(x1, 0), RW - 1);
    float v00 = __half2float(inr[(y0 * RW + x0) * CS + c]);
    float v01 = __half2float(inr[(y0 * RW + x1) * CS + c]);
    float v10 = __half2float(inr[(y1 * RW + x0) * CS + c]);
    float v11 = __half2float(inr[(y1 * RW + x1) * CS + c]);
    float v0 = v00 + tx * (v01 - v00);
    float v1 = v10 + tx * (v11 - v10);
    out[idx] = v0 + ty * (v1 - v0);
}

extern "C" void kernel_launch(void* const* d_in, const int* in_sizes, int n_in,
                              void* d_out, int out_size, void* d_ws, size_t ws_size,
                              hipStream_t stream) {
    const float* src = (const float*)d_in[0];   // (1,512,512,21) f32
    const float* im  = (const float*)d_in[1];   // (1,512,512,3)  f32
    float* out = (float*)d_out;                 // (1,512,512,21) f32 = 22,020,096 B
    char* ws = (char*)d_ws;

    // scratch in d_out (fully overwritten by K3 at the end, stream-ordered):
    __half* tmpH = (__half*)d_out;                      // [512][160][21] fp16 = 3,440,640 B
    float* part  = (float*)d_out;                       // [13][21][16384] f32 = 17,891,328 B (after tmpH consumed)
    __half* srcP = (__half*)((char*)d_out + 17891328);  // [21][128][160] fp16 = 860,160 B (ends 18,751,488 < 22 MB)
    // small scratch in ws (843,776 B):
    __half* imh  = (__half*)ws;                         // [128][152][4] fp16 = 155,648 B
    __half* out_r = (__half*)(ws + 155648);             // [16384][21] fp16   = 688,128 B

    int th = IH * SPITCH * CS;
    ds_src_h_kernel<<<(th + 255) / 256, 256, 0, stream>>>(src, tmpH);
    int tv = RH * SPITCH * CS;
    ds_src_v_kernel<<<(tv + 255) / 256, 256, 0, stream>>>(tmpH, srcP);
    int t2 = RH * IPITCH;
    downsample_im_kernel<<<(t2 + 255) / 256, 256, 0, stream>>>(im, imh);

    // 3328 waves = 832 blocks of 4 waves (R5-proven shape)
    bilateral_kernel<<<832, 256, 0, stream>>>(srcP, (const float2*)imh, part);

    int tr = CS * NPIX;
    reduce_kernel<<<(tr + 255) / 256, 256, 0, stream>>>(part, out_r);

    int t3 = IH * IW * CS;
    upsample_kernel<<<(t3 + 255) / 256, 256, 0, stream>>>(out_r, out, t3);
}

// Round 9
// 80.916 us; speedup vs baseline: 1.1387x; 1.1387x over previous
//
#include <hip/hip_runtime.h>

#define RH 128
#define RW 128
#define CS 21    // src channels
#define CG 6     // packed channel groups (24 ch incl 3 zero pads)
#define IH 512
#define IW 512
#define NPIX (RH * RW)
#define P 13         // dy split factor
#define SPITCH 160   // padded row pitch: 12 zero | 128 | 20 zero
#define SCH4 (RH * SPITCH)  // per-cgroup plane stride in float4 units
#define IPITCH 152   // padded im row pitch (float4): 12 reflect | 128 | 12 reflect

// ---------------- K1: grid-fused {horizontal src downsample} + {im downsample} ----------------
#define NB_H ((IH * SPITCH * CS + 255) / 256)   // 6720 blocks for ds_h
__global__ void fused_ds_kernel(const float* __restrict__ src, const float* __restrict__ im,
                                float* __restrict__ tmpH, float4* __restrict__ im4P) {
    if (blockIdx.x < NB_H) {
        int idx = blockIdx.x * 256 + threadIdx.x;
        if (idx >= IH * SPITCH * CS) return;
        int c = idx % CS;
        int t = idx / CS;
        int xp = t % SPITCH;
        int y = t / SPITCH;                 // input row 0..511
        int x = xp - 12;
        if (x < 0 || x >= RW) { tmpH[idx] = 0.f; return; }

        float sx = 4.f * x + 1.5f;
        float wx[8]; int jx[8]; float wxs = 0.f;
#pragma unroll
        for (int k = 0; k < 8; ++k) {
            int j = 4 * x - 2 + k;
            float w = 1.f - fabsf(sx - (float)j) * 0.25f;
            if (j < 0 || j >= IW) { w = 0.f; j = 0; }
            jx[k] = j; wx[k] = w; wxs += w;
        }
        const float* row = src + (size_t)y * IW * CS + c;
        float s = 0.f;
#pragma unroll
        for (int b = 0; b < 8; ++b) s += wx[b] * row[jx[b] * CS];
        tmpH[idx] = s / wxs;
    } else {
        int idx = (blockIdx.x - NB_H) * 256 + threadIdx.x;
        if (idx >= RH * IPITCH) return;
        int xp = idx % IPITCH;
        int y = idx / IPITCH;
        int gx = xp - 12;
        gx = gx < 0 ? -gx : (gx > RW - 1 ? 2 * (RW - 1) - gx : gx);

        float wy[8], wx[8];
        int jy[8], jx[8];
        float sy = 4.f * y + 1.5f, sx = 4.f * gx + 1.5f;
        float wys = 0.f, wxs = 0.f;
#pragma unroll
        for (int k = 0; k < 8; ++k) {
            int j = 4 * y - 2 + k;
            float w = 1.f - fabsf(sy - (float)j) * 0.25f;
            if (j < 0 || j >= IH) { w = 0.f; j = 0; }
            jy[k] = j; wy[k] = w; wys += w;
            int j2 = 4 * gx - 2 + k;
            float w2 = 1.f - fabsf(sx - (float)j2) * 0.25f;
            if (j2 < 0 || j2 >= IW) { w2 = 0.f; j2 = 0; }
            jx[k] = j2; wx[k] = w2; wxs += w2;
        }
        float inv = 1.f / (wys * wxs);
        float s0 = 0.f, s1 = 0.f, s2 = 0.f;
#pragma unroll
        for (int a = 0; a < 8; ++a) {
            const float* row = im + (size_t)(jy[a] * IW) * 3;
            float r0 = 0.f, r1 = 0.f, r2 = 0.f;
#pragma unroll
            for (int b = 0; b < 8; ++b) {
                const float* pp = row + jx[b] * 3;
                r0 += wx[b] * pp[0];
                r1 += wx[b] * pp[1];
                r2 += wx[b] * pp[2];
            }
            s0 += wy[a] * r0; s1 += wy[a] * r1; s2 += wy[a] * r2;
        }
        im4P[idx] = make_float4(s0 * inv, s1 * inv, s2 * inv, 0.f);
    }
}

// ---------------- K1a-V: vertical pass tmpH -> packed planar srcP4[6][128][160] float4 ----------------
__global__ void ds_src_v_kernel(const float* __restrict__ tmpH, float* __restrict__ srcP) {
    int idx = blockIdx.x * blockDim.x + threadIdx.x;
    if (idx >= RH * SPITCH * (CG * 4)) return;
    int c = idx % (CG * 4);
    int t = idx / (CG * 4);
    int xp = t % SPITCH;
    int y = t / SPITCH;                 // output row 0..127
    size_t oidx = ((size_t)((c >> 2) * RH + y) * SPITCH + xp) * 4 + (c & 3);
    if (c >= CS) { srcP[oidx] = 0.f; return; }   // pad channels 21..23

    float sy = 4.f * y + 1.5f;
    float wy[8]; int jy[8]; float wys = 0.f;
#pragma unroll
    for (int k = 0; k < 8; ++k) {
        int j = 4 * y - 2 + k;
        float w = 1.f - fabsf(sy - (float)j) * 0.25f;
        if (j < 0 || j >= IH) { w = 0.f; j = 0; }
        jy[k] = j; wy[k] = w; wys += w;
    }
    float s = 0.f;
#pragma unroll
    for (int a = 0; a < 8; ++a)
        s += wy[a] * tmpH[((size_t)jy[a] * SPITCH + xp) * CS + c];
    srcP[oidx] = s / wys;
}

// ---------------- K2: joint bilateral; packed float4 src; 4-wave dx-split + LDS combine ----------------
// Block = 256 thr = 4 waves over the same 64 pixels; wave w handles dx = w, w+4, ...
// Blocks: 13 (dy groups) x 256 (half-rows). All loads perfectly coalesced float4.
__global__ __launch_bounds__(256) void bilateral_kernel(
        const float4* __restrict__ srcP4,  // [6][128][160] packed channels, zero-padded
        const float4* __restrict__ im4P,   // [128][152] reflect-padded
        float* __restrict__ part) {        // [13][21][NPIX]
    __shared__ float4 red[3][CG][64];      // waves 1..3 partial accs (18.4 KB)

    int tid = threadIdx.x;
    int w = tid >> 6;                      // dx quarter 0..3
    int lane = tid & 63;
    int bid = blockIdx.x;
    int p = bid >> 8;                      // 0..12
    int pxw = bid & 255;
    int h = pxw & 1;
    int y = pxw >> 1;
    int x = (h << 6) + lane;

    float4 q0 = im4P[y * IPITCH + x + 12];
    float c0 = q0.x, c1 = q0.y, c2 = q0.z;

    float4 a0 = {0,0,0,0}, a1 = {0,0,0,0}, a2 = {0,0,0,0},
           a3 = {0,0,0,0}, a4 = {0,0,0,0}, a5 = {0,0,0,0};

    for (int dy = p; dy < 25; dy += P) {
        int ry = y + dy - 12;
        if (ry < 0 || ry >= RH) continue;   // block-uniform; src zero-pad handles x
        float fdy = (float)(dy - 12);
        float gy = fdy * fdy;
        const float4* srow = srcP4 + ry * SPITCH + x;   // + cg*SCH4 + dx
        const float4* irow = im4P + ry * IPITCH + x;    // + dx
        for (int dx = w; dx < 25; dx += 4) {
            float4 q = irow[dx];
            float d0 = q.x - c0, d1 = q.y - c1, d2 = q.z - c2;
            float fdx = (float)(dx - 12);
            float e = -(d0 * d0 + d1 * d1 + d2 * d2) * (1.f / 18.f)
                      - (gy + fdx * fdx) * (1.f / 128.f);
            float cw = __expf(e);
            const float4* sp = srow + dx;
            float4 s0 = sp[0], s1 = sp[SCH4], s2 = sp[2 * SCH4],
                   s3 = sp[3 * SCH4], s4 = sp[4 * SCH4], s5 = sp[5 * SCH4];
            a0.x = fmaf(cw, s0.x, a0.x); a0.y = fmaf(cw, s0.y, a0.y);
            a0.z = fmaf(cw, s0.z, a0.z); a0.w = fmaf(cw, s0.w, a0.w);
            a1.x = fmaf(cw, s1.x, a1.x); a1.y = fmaf(cw, s1.y, a1.y);
            a1.z = fmaf(cw, s1.z, a1.z); a1.w = fmaf(cw, s1.w, a1.w);
            a2.x = fmaf(cw, s2.x, a2.x); a2.y = fmaf(cw, s2.y, a2.y);
            a2.z = fmaf(cw, s2.z, a2.z); a2.w = fmaf(cw, s2.w, a2.w);
            a3.x = fmaf(cw, s3.x, a3.x); a3.y = fmaf(cw, s3.y, a3.y);
            a3.z = fmaf(cw, s3.z, a3.z); a3.w = fmaf(cw, s3.w, a3.w);
            a4.x = fmaf(cw, s4.x, a4.x); a4.y = fmaf(cw, s4.y, a4.y);
            a4.z = fmaf(cw, s4.z, a4.z); a4.w = fmaf(cw, s4.w, a4.w);
            a5.x = fmaf(cw, s5.x, a5.x); a5.y = fmaf(cw, s5.y, a5.y);
            a5.z = fmaf(cw, s5.z, a5.z); a5.w = fmaf(cw, s5.w, a5.w);
        }
    }

    if (w > 0) {
        red[w - 1][0][lane] = a0; red[w - 1][1][lane] = a1; red[w - 1][2][lane] = a2;
        red[w - 1][3][lane] = a3; red[w - 1][4][lane] = a4; red[w - 1][5][lane] = a5;
    }
    __syncthreads();
    if (w == 0) {
        float4 b[CG] = {a0, a1, a2, a3, a4, a5};
#pragma unroll
        for (int k = 0; k < CG; ++k) {
#pragma unroll
            for (int r = 0; r < 3; ++r) {
                float4 v = red[r][k][lane];
                b[k].x += v.x; b[k].y += v.y; b[k].z += v.z; b[k].w += v.w;
            }
        }
        int pix = (y << 7) + x;
        float* po = part + ((size_t)(p * CS) << 14) + pix;
#pragma unroll
        for (int c = 0; c < CS; ++c) {
            float v = (&b[c >> 2].x)[c & 3];
            po[(size_t)c << 14] = v;
        }
    }
}

// ---------------- K2b: reduce partials (float4 over pixels) ----------------
__global__ void reduce_kernel(const float4* __restrict__ part4, float* __restrict__ outr) {
    int t = blockIdx.x * blockDim.x + threadIdx.x;
    if (t >= CS * (NPIX / 4)) return;
    int c = t >> 12;                 // 0..20
    int i4 = t & 4095;
    float4 s = {0, 0, 0, 0};
#pragma unroll
    for (int p = 0; p < P; ++p) {
        float4 v = part4[((size_t)(p * CS + c) << 12) + i4];
        s.x += v.x; s.y += v.y; s.z += v.z; s.w += v.w;
    }
    int pix0 = i4 << 2;
    outr[(size_t)(pix0 + 0) * CS + c] = s.x;
    outr[(size_t)(pix0 + 1) * CS + c] = s.y;
    outr[(size_t)(pix0 + 2) * CS + c] = s.z;
    outr[(size_t)(pix0 + 3) * CS + c] = s.w;
}

// ---------------- K3: bilinear upsample 128 -> 512 ----------------
__global__ void upsample_kernel(const float* __restrict__ inr, float* __restrict__ out, int total) {
    int idx = blockIdx.x * blockDim.x + threadIdx.x;
    if (idx >= total) return;
    int c = idx % CS;
    int t = idx / CS;
    int X = t % IW, Y = t / IW;
    float fy = 0.25f * (float)Y - 0.375f;
    float fx = 0.25f * (float)X - 0.375f;
    int y0 = (int)floorf(fy); float ty = fy - (float)y0;
    int x0 = (int)floorf(fx); float tx = fx - (float)x0;
    int y1 = y0 + 1, x1 = x0 + 1;
    y0 = min(max(y0, 0), RH - 1); y1 = min(max(y1, 0), RH - 1);
    x0 = min(max(x0, 0), RW - 1); x1 = min(max(x1, 0), RW - 1);
    float v00 = inr[(y0 * RW + x0) * CS + c], v01 = inr[(y0 * RW + x1) * CS + c];
    float v10 = inr[(y1 * RW + x0) * CS + c], v11 = inr[(y1 * RW + x1) * CS + c];
    float v0 = v00 + tx * (v01 - v00);
    float v1 = v10 + tx * (v11 - v10);
    out[idx] = v0 + ty * (v1 - v0);
}

extern "C" void kernel_launch(void* const* d_in, const int* in_sizes, int n_in,
                              void* d_out, int out_size, void* d_ws, size_t ws_size,
                              hipStream_t stream) {
    const float* src = (const float*)d_in[0];   // (1,512,512,21) f32
    const float* im  = (const float*)d_in[1];   // (1,512,512,3)  f32
    float* out = (float*)d_out;                 // (1,512,512,21) f32 = 22,020,096 B
    char* ws = (char*)d_ws;

    // scratch in d_out (fully overwritten by K3 at the end, stream-ordered):
    float* tmpH  = (float*)d_out;                       // [512][160][21] f32 = 6,881,280 B
    float* part  = (float*)d_out;                       // [13][21][16384] f32 = 17,891,328 B (after tmpH consumed)
    float* srcP  = (float*)((char*)d_out + 20054016);   // [6][128][160] float4 = 1,966,080 B (tail, exact fit)
    // small scratch in ws (1,687,552 B):
    float4* im4P = (float4*)ws;                         // [128][152] float4 = 311,296 B
    float* out_r = (float*)(ws + 311296);               // [16384][21] f32   = 1,376,256 B

    int nb_im = (RH * IPITCH + 255) / 256;
    fused_ds_kernel<<<NB_H + nb_im, 256, 0, stream>>>(src, im, tmpH, im4P);

    int tv = RH * SPITCH * (CG * 4);
    ds_src_v_kernel<<<(tv + 255) / 256, 256, 0, stream>>>(tmpH, srcP);

    // 13 dy-groups x 256 half-rows = 3328 blocks x 4 waves = 13312 waves
    bilateral_kernel<<<13 * 256, 256, 0, stream>>>((const float4*)srcP, im4P, part);

    int tr = CS * (NPIX / 4);
    reduce_kernel<<<(tr + 255) / 256, 256, 0, stream>>>((const float4*)part, out_r);

    int t3 = IH * IW * CS;
    upsample_kernel<<<(t3 + 255) / 256, 256, 0, stream>>>(out_r, out, t3);
}

// Round 10
// 70.540 us; speedup vs baseline: 1.3062x; 1.1471x over previous
//
#include <hip/hip_runtime.h>
#include <hip/hip_fp16.h>

#define RH 128
#define RW 128
#define CS 21    // src channels
#define IH 512
#define IW 512
#define NPIX (RH * RW)
#define P 13         // dy split factor
#define SPITCH 160   // padded row pitch: 12 zero | 128 | 20 zero
#define SCH8 (RH * SPITCH)  // per-group plane stride in half8 units
#define IPITCH 152   // padded im row pitch: 12 reflect | 128 | 12 reflect

// ---------------- K1: grid-fused {horizontal src downsample (fp32)} + {im downsample (half4)} ----------------
#define NB_H ((IH * SPITCH * CS + 255) / 256)   // blocks for ds_h part
__global__ void fused_ds_kernel(const float* __restrict__ src, const float* __restrict__ im,
                                float* __restrict__ tmpH, float2* __restrict__ imh) {
    if (blockIdx.x < NB_H) {
        int idx = blockIdx.x * 256 + threadIdx.x;
        if (idx >= IH * SPITCH * CS) return;
        int c = idx % CS;
        int t = idx / CS;
        int xp = t % SPITCH;
        int y = t / SPITCH;                 // input row 0..511
        int x = xp - 12;
        if (x < 0 || x >= RW) { tmpH[idx] = 0.f; return; }

        float sx = 4.f * x + 1.5f;
        float wx[8]; int jx[8]; float wxs = 0.f;
#pragma unroll
        for (int k = 0; k < 8; ++k) {
            int j = 4 * x - 2 + k;
            float w = 1.f - fabsf(sx - (float)j) * 0.25f;
            if (j < 0 || j >= IW) { w = 0.f; j = 0; }
            jx[k] = j; wx[k] = w; wxs += w;
        }
        const float* row = src + (size_t)y * IW * CS + c;
        float s = 0.f;
#pragma unroll
        for (int b = 0; b < 8; ++b) s += wx[b] * row[jx[b] * CS];
        tmpH[idx] = s / wxs;
    } else {
        int idx = (blockIdx.x - NB_H) * 256 + threadIdx.x;
        if (idx >= RH * IPITCH) return;
        int xp = idx % IPITCH;
        int y = idx / IPITCH;
        int gx = xp - 12;
        gx = gx < 0 ? -gx : (gx > RW - 1 ? 2 * (RW - 1) - gx : gx);

        float wy[8], wx[8];
        int jy[8], jx[8];
        float sy = 4.f * y + 1.5f, sx = 4.f * gx + 1.5f;
        float wys = 0.f, wxs = 0.f;
#pragma unroll
        for (int k = 0; k < 8; ++k) {
            int j = 4 * y - 2 + k;
            float w = 1.f - fabsf(sy - (float)j) * 0.25f;
            if (j < 0 || j >= IH) { w = 0.f; j = 0; }
            jy[k] = j; wy[k] = w; wys += w;
            int j2 = 4 * gx - 2 + k;
            float w2 = 1.f - fabsf(sx - (float)j2) * 0.25f;
            if (j2 < 0 || j2 >= IW) { w2 = 0.f; j2 = 0; }
            jx[k] = j2; wx[k] = w2; wxs += w2;
        }
        float inv = 1.f / (wys * wxs);
        float s0 = 0.f, s1 = 0.f, s2 = 0.f;
#pragma unroll
        for (int a = 0; a < 8; ++a) {
            const float* row = im + (size_t)(jy[a] * IW) * 3;
            float r0 = 0.f, r1 = 0.f, r2 = 0.f;
#pragma unroll
            for (int b = 0; b < 8; ++b) {
                const float* pp = row + jx[b] * 3;
                r0 += wx[b] * pp[0];
                r1 += wx[b] * pp[1];
                r2 += wx[b] * pp[2];
            }
            s0 += wy[a] * r0; s1 += wy[a] * r1; s2 += wy[a] * r2;
        }
        float2 o;
        *reinterpret_cast<__half2*>(&o.x) = __floats2half2_rn(s0 * inv, s1 * inv);
        *reinterpret_cast<__half2*>(&o.y) = __floats2half2_rn(s2 * inv, 0.f);
        imh[idx] = o;
    }
}

// ---------------- K1a-V: vertical pass tmpH(fp32) -> packed half8 planar srcP[3][128][160] ----------------
__global__ void ds_src_v_kernel(const float* __restrict__ tmpH, __half* __restrict__ srcP) {
    int idx = blockIdx.x * blockDim.x + threadIdx.x;
    if (idx >= RH * SPITCH * 24) return;
    int c = idx % 24;
    int t = idx / 24;
    int xp = t % SPITCH;
    int y = t / SPITCH;                 // output row 0..127
    int g = c >> 3;
    size_t oidx = ((size_t)(g * RH + y) * SPITCH + xp) * 8 + (c & 7);
    int x = xp - 12;
    if (c >= CS || x < 0 || x >= RW) { srcP[oidx] = __float2half(0.f); return; }

    float sy = 4.f * y + 1.5f;
    float wy[8]; int jy[8]; float wys = 0.f;
#pragma unroll
    for (int k = 0; k < 8; ++k) {
        int j = 4 * y - 2 + k;
        float w = 1.f - fabsf(sy - (float)j) * 0.25f;
        if (j < 0 || j >= IH) { w = 0.f; j = 0; }
        jy[k] = j; wy[k] = w; wys += w;
    }
    float s = 0.f;
#pragma unroll
    for (int a = 0; a < 8; ++a)
        s += wy[a] * tmpH[((size_t)jy[a] * SPITCH + xp) * CS + c];
    srcP[oidx] = __float2half(s / wys);
}

// ---------------- K2: joint bilateral; half8-packed src; 4-wave dx-split + LDS combine ----------------
__global__ __launch_bounds__(256) void bilateral_kernel(
        const float4* __restrict__ srcP8,  // [3][128][160] half8 elements, zero-padded
        const float2* __restrict__ imh,    // [128][152] half4 elements, reflect-padded
        float* __restrict__ part) {        // [13][21][NPIX] f32
    __shared__ float4 red[3][6][64];       // waves 1..3 partial accs (18.4 KB)

    int tid = threadIdx.x;
    int w = tid >> 6;                      // dx quarter 0..3
    int lane = tid & 63;
    int bid = blockIdx.x;
    int p = bid >> 8;                      // 0..12
    int pxw = bid & 255;
    int h = pxw & 1;
    int y = pxw >> 1;
    int x = (h << 6) + lane;

    float2 craw = imh[y * IPITCH + x + 12];
    __half2 ch01 = *reinterpret_cast<__half2*>(&craw.x);
    __half2 ch23 = *reinterpret_cast<__half2*>(&craw.y);
    float2 f01 = __half22float2(ch01);
    float c0 = f01.x, c1 = f01.y, c2 = __half2float(__low2half(ch23));

    float4 a0 = {0,0,0,0}, a1 = {0,0,0,0}, a2 = {0,0,0,0},
           a3 = {0,0,0,0}, a4 = {0,0,0,0}, a5 = {0,0,0,0};

    for (int dy = p; dy < 25; dy += P) {
        int ry = y + dy - 12;
        if (ry < 0 || ry >= RH) continue;   // block-uniform; src zero-pad handles x
        float fdy = (float)(dy - 12);
        float gy = fdy * fdy;
        const float4* srow = srcP8 + ry * SPITCH + x;   // + g*SCH8 + dx
        const float2* irow = imh + ry * IPITCH + x;     // + dx

        __half2 hacc[12];
#pragma unroll
        for (int k = 0; k < 12; ++k) hacc[k] = __floats2half2_rn(0.f, 0.f);

        for (int dx = w; dx < 25; dx += 4) {
            float2 raw = irow[dx];
            __half2 h01 = *reinterpret_cast<__half2*>(&raw.x);
            __half2 h23 = *reinterpret_cast<__half2*>(&raw.y);
            float2 rg = __half22float2(h01);
            float d0 = rg.x - c0;
            float d1 = rg.y - c1;
            float d2 = __half2float(__low2half(h23)) - c2;
            float fdx = (float)(dx - 12);
            float e = -(d0 * d0 + d1 * d1 + d2 * d2) * (1.f / 18.f)
                      - (gy + fdx * fdx) * (1.f / 128.f);
            float cw = __expf(e);
            __half2 cw2 = __float2half2_rn(cw);

            float4 s0 = srow[dx];
            float4 s1 = srow[SCH8 + dx];
            float4 s2 = srow[2 * SCH8 + dx];
            const __half2* h0 = reinterpret_cast<const __half2*>(&s0);
            const __half2* h1 = reinterpret_cast<const __half2*>(&s1);
            const __half2* h2 = reinterpret_cast<const __half2*>(&s2);
#pragma unroll
            for (int k = 0; k < 4; ++k) {
                hacc[k]     = __hfma2(cw2, h0[k], hacc[k]);
                hacc[4 + k] = __hfma2(cw2, h1[k], hacc[4 + k]);
                hacc[8 + k] = __hfma2(cw2, h2[k], hacc[8 + k]);
            }
        }
        // unpack per-dy into fp32 accumulators
        float2 u;
        u = __half22float2(hacc[0]);  a0.x += u.x; a0.y += u.y;
        u = __half22float2(hacc[1]);  a0.z += u.x; a0.w += u.y;
        u = __half22float2(hacc[2]);  a1.x += u.x; a1.y += u.y;
        u = __half22float2(hacc[3]);  a1.z += u.x; a1.w += u.y;
        u = __half22float2(hacc[4]);  a2.x += u.x; a2.y += u.y;
        u = __half22float2(hacc[5]);  a2.z += u.x; a2.w += u.y;
        u = __half22float2(hacc[6]);  a3.x += u.x; a3.y += u.y;
        u = __half22float2(hacc[7]);  a3.z += u.x; a3.w += u.y;
        u = __half22float2(hacc[8]);  a4.x += u.x; a4.y += u.y;
        u = __half22float2(hacc[9]);  a4.z += u.x; a4.w += u.y;
        u = __half22float2(hacc[10]); a5.x += u.x; a5.y += u.y;
        u = __half22float2(hacc[11]); a5.z += u.x; a5.w += u.y;
    }

    if (w > 0) {
        red[w - 1][0][lane] = a0; red[w - 1][1][lane] = a1; red[w - 1][2][lane] = a2;
        red[w - 1][3][lane] = a3; red[w - 1][4][lane] = a4; red[w - 1][5][lane] = a5;
    }
    __syncthreads();
    if (w == 0) {
        float4 b[6] = {a0, a1, a2, a3, a4, a5};
#pragma unroll
        for (int k = 0; k < 6; ++k) {
#pragma unroll
            for (int r = 0; r < 3; ++r) {
                float4 v = red[r][k][lane];
                b[k].x += v.x; b[k].y += v.y; b[k].z += v.z; b[k].w += v.w;
            }
        }
        int pix = (y << 7) + x;
        float* po = part + ((size_t)(p * CS) << 14) + pix;
#pragma unroll
        for (int c = 0; c < CS; ++c) {
            float v = (&b[c >> 2].x)[c & 3];
            po[(size_t)c << 14] = v;
        }
    }
}

// ---------------- K2b: reduce partials (float4 over pixels) ----------------
__global__ void reduce_kernel(const float4* __restrict__ part4, float* __restrict__ outr) {
    int t = blockIdx.x * blockDim.x + threadIdx.x;
    if (t >= CS * (NPIX / 4)) return;
    int c = t >> 12;                 // 0..20
    int i4 = t & 4095;
    float4 s = {0, 0, 0, 0};
#pragma unroll
    for (int p = 0; p < P; ++p) {
        float4 v = part4[((size_t)(p * CS + c) << 12) + i4];
        s.x += v.x; s.y += v.y; s.z += v.z; s.w += v.w;
    }
    int pix0 = i4 << 2;
    outr[(size_t)(pix0 + 0) * CS + c] = s.x;
    outr[(size_t)(pix0 + 1) * CS + c] = s.y;
    outr[(size_t)(pix0 + 2) * CS + c] = s.z;
    outr[(size_t)(pix0 + 3) * CS + c] = s.w;
}

// ---------------- K3: bilinear upsample 128 -> 512 ----------------
__global__ void upsample_kernel(const float* __restrict__ inr, float* __restrict__ out, int total) {
    int idx = blockIdx.x * blockDim.x + threadIdx.x;
    if (idx >= total) return;
    int c = idx % CS;
    int t = idx / CS;
    int X = t % IW, Y = t / IW;
    float fy = 0.25f * (float)Y - 0.375f;
    float fx = 0.25f * (float)X - 0.375f;
    int y0 = (int)floorf(fy); float ty = fy - (float)y0;
    int x0 = (int)floorf(fx); float tx = fx - (float)x0;
    int y1 = y0 + 1, x1 = x0 + 1;
    y0 = min(max(y0, 0), RH - 1); y1 = min(max(y1, 0), RH - 1);
    x0 = min(max(x0, 0), RW - 1); x1 = min(max(x1, 0), RW - 1);
    float v00 = inr[(y0 * RW + x0) * CS + c], v01 = inr[(y0 * RW + x1) * CS + c];
    float v10 = inr[(y1 * RW + x0) * CS + c], v11 = inr[(y1 * RW + x1) * CS + c];
    float v0 = v00 + tx * (v01 - v00);
    float v1 = v10 + tx * (v11 - v10);
    out[idx] = v0 + ty * (v1 - v0);
}

extern "C" void kernel_launch(void* const* d_in, const int* in_sizes, int n_in,
                              void* d_out, int out_size, void* d_ws, size_t ws_size,
                              hipStream_t stream) {
    const float* src = (const float*)d_in[0];   // (1,512,512,21) f32
    const float* im  = (const float*)d_in[1];   // (1,512,512,3)  f32
    float* out = (float*)d_out;                 // (1,512,512,21) f32 = 22,020,096 B
    char* ws = (char*)d_ws;

    // scratch in d_out (fully overwritten by K3 at the end, stream-ordered):
    float* tmpH  = (float*)d_out;                       // [512][160][21] f32 = 6,881,280 B
    float* part  = (float*)d_out;                       // [13][21][16384] f32 = 17,891,328 B (after tmpH consumed)
    __half* srcP = (__half*)((char*)d_out + 21037056);  // [3][128][160] half8 = 983,040 B (ends exactly 22,020,096)
    // small scratch in ws (1,531,904 B):
    float2* imh  = (float2*)ws;                         // [128][152] half4 = 155,648 B
    float* out_r = (float*)(ws + 155648);               // [16384][21] f32  = 1,376,256 B

    int nb_im = (RH * IPITCH + 255) / 256;
    fused_ds_kernel<<<NB_H + nb_im, 256, 0, stream>>>(src, im, tmpH, imh);

    int tv = RH * SPITCH * 24;
    ds_src_v_kernel<<<(tv + 255) / 256, 256, 0, stream>>>(tmpH, srcP);

    // 13 dy-groups x 256 half-rows = 3328 blocks x 4 waves
    bilateral_kernel<<<13 * 256, 256, 0, stream>>>((const float4*)srcP, imh, part);

    int tr = CS * (NPIX / 4);
    reduce_kernel<<<(tr + 255) / 256, 256, 0, stream>>>((const float4*)part, out_r);

    int t3 = IH * IW * CS;
    upsample_kernel<<<(t3 + 255) / 256, 256, 0, stream>>>(out_r, out, t3);
}